// Round 10
// baseline (147.308 us; speedup 1.0000x reference)
//
#include <hip/hip_runtime.h>
#include <hip/hip_bf16.h>
#include <cstdint>
#include <cstddef>

// Problem constants: B=32, N=768, D=768
#define BN_ROWS 24576
#define DD 768
#define BE (768*768)
#define BM 192
#define BN_T 192
#define BK 32
#define ABUF 12288            // A region bytes per buffer (192 rows x 64B)
#define BUFSZ 24576           // A (12288) + B (12288)

typedef __attribute__((ext_vector_type(8))) short bf16x8;
typedef __attribute__((ext_vector_type(4))) float f32x4;

static __device__ __forceinline__ unsigned short f2bf(float f) {
  unsigned int u = __builtin_bit_cast(unsigned int, f);
  unsigned int lsb = (u >> 16) & 1u;
  u += 0x7fffu + lsb;
  return (unsigned short)(u >> 16);
}

// ---------------- fused prep kernel (MLP-maximized) ----------------
// Sections by blockIdx:
//   [0, 2304)        convertX: 8 independent float4 loads/thread, exact fit
//   [2304, 2448)     convertWT: 64x64 LDS transpose tiles
//   [2448, 5520)     adjNorm: 2 rows/wave, 6 loads in flight, dual reduce

#define PREP_CX 2304
#define PREP_WT 144
#define PREP_AN 3072
#define CX_STRIDE (PREP_CX * 256)   // 589824; n4 = 8 * CX_STRIDE exactly

__global__ __launch_bounds__(256) void prep(const float* __restrict__ X,
                                            const float* __restrict__ adj,
                                            const float* __restrict__ Wl,
                                            const float* __restrict__ Wl1,
                                            unsigned short* __restrict__ Xb,
                                            unsigned short* __restrict__ adjnb,
                                            unsigned short* __restrict__ WlT,
                                            unsigned short* __restrict__ Wl1T) {
  __shared__ float tile[64][65];
  const int bid = blockIdx.x;

  if (bid < PREP_CX) {
    const int i0 = bid * 256 + threadIdx.x;
    const float4* in = reinterpret_cast<const float4*>(X);
    ushort4* outp = reinterpret_cast<ushort4*>(Xb);
    float4 v[8];
    #pragma unroll
    for (int j = 0; j < 8; ++j) v[j] = in[i0 + j * CX_STRIDE];   // 8 independent loads
    #pragma unroll
    for (int j = 0; j < 8; ++j) {
      ushort4 o;
      o.x = f2bf(v[j].x); o.y = f2bf(v[j].y); o.z = f2bf(v[j].z); o.w = f2bf(v[j].w);
      outp[i0 + j * CX_STRIDE] = o;
    }
  } else if (bid < PREP_CX + PREP_WT) {
    const int tb = bid - PREP_CX;
    const int tr = tb / 12, tc = tb % 12;
    const int c = threadIdx.x & 63, r0 = threadIdx.x >> 6;
    const float* srcs[2] = {Wl, Wl1};
    unsigned short* dsts[2] = {WlT, Wl1T};
    #pragma unroll
    for (int m = 0; m < 2; ++m) {
      const float* src = srcs[m];
      #pragma unroll
      for (int i = 0; i < 16; ++i) {
        int r = r0 + i * 4;
        tile[r][c] = src[(size_t)(tr * 64 + r) * DD + tc * 64 + c];
      }
      __syncthreads();
      unsigned short* dst = dsts[m];
      #pragma unroll
      for (int i = 0; i < 16; ++i) {
        int r2 = r0 + i * 4;
        dst[(size_t)(tc * 64 + r2) * DD + tr * 64 + c] = f2bf(tile[c][r2]);
      }
      __syncthreads();
    }
  } else {
    const int rb = bid - (PREP_CX + PREP_WT);
    const int wid = threadIdx.x >> 6, lane = threadIdx.x & 63;
    const int row0 = rb * 8 + wid * 2;          // 2 rows per wave
    const float4* a0 = reinterpret_cast<const float4*>(adj + (size_t)row0 * DD);
    const float4* a1 = reinterpret_cast<const float4*>(adj + (size_t)(row0 + 1) * DD);
    float4 u[3], w[3];
    #pragma unroll
    for (int i = 0; i < 3; ++i) u[i] = a0[i * 64 + lane];   // 6 independent loads
    #pragma unroll
    for (int i = 0; i < 3; ++i) w[i] = a1[i * 64 + lane];
    float s0 = 0.f, s1 = 0.f;
    #pragma unroll
    for (int i = 0; i < 3; ++i) {
      s0 += (u[i].x + u[i].y) + (u[i].z + u[i].w);
      s1 += (w[i].x + w[i].y) + (w[i].z + w[i].w);
    }
    #pragma unroll
    for (int off = 32; off; off >>= 1) {        // dual interleaved chains
      s0 += __shfl_down(s0, off);
      s1 += __shfl_down(s1, off);
    }
    s0 = __shfl(s0, 0); s1 = __shfl(s1, 0);
    float r0i = (s0 == 0.f) ? 0.f : 1.f / s0;
    float r1i = (s1 == 0.f) ? 0.f : 1.f / s1;
    ushort4* o0 = reinterpret_cast<ushort4*>(adjnb + (size_t)row0 * DD);
    ushort4* o1 = reinterpret_cast<ushort4*>(adjnb + (size_t)(row0 + 1) * DD);
    #pragma unroll
    for (int i = 0; i < 3; ++i) {
      ushort4 p, q;
      p.x = f2bf(u[i].x * r0i); p.y = f2bf(u[i].y * r0i);
      p.z = f2bf(u[i].z * r0i); p.w = f2bf(u[i].w * r0i);
      q.x = f2bf(w[i].x * r1i); q.y = f2bf(w[i].y * r1i);
      q.z = f2bf(w[i].z * r1i); q.w = f2bf(w[i].w * r1i);
      o0[i * 64 + lane] = p;
      o1[i * 64 + lane] = q;
    }
  }
}

// ----- 4-wave 192x192 BK=32 dbuf GEMM, 2 independent blocks per CU -----
// (unchanged from R9)
// Per K-tile t: { vmcnt(0); s_barrier; stage(t+1) at top (max slack);
//   12 ds_read a0..a5,b0..b5; 36 MFMA ni-outer (progressive lgkm drain) }.
// MODE 0: e1 = Xb @ W1T, transposed bf16 store (NT=24)
// MODE 1: out = leaky( adjnb@e1 + Xb@Wl ), fused 48-tile K-loop, fp32 store

template<int MODE>
__global__ __launch_bounds__(256, 2) void gemm4(
    const unsigned short* __restrict__ P0,  // MODE0: Xb     MODE1: adjnb
    const unsigned short* __restrict__ P1,  // MODE0: W1T    MODE1: e1T
    const unsigned short* __restrict__ P2,  // MODE1: Xb
    const unsigned short* __restrict__ P3,  // MODE1: WlT
    void* __restrict__ outp)
{
  __shared__ char smem[2 * BUFSZ];
  constexpr int NT = MODE ? 48 : 24;
  const int tid = threadIdx.x, lane = tid & 63;
  const int wid = tid >> 6;
  const int wr = wid >> 1, wc = wid & 1;      // wave tile 96x96

  // XCD-chunked bijective logical id (grid 512 = 8 XCD x 64)
  const int logical = (blockIdx.x & 7) * 64 + (blockIdx.x >> 3);

  const unsigned short *Ab0, *Bb0, *Ab1 = nullptr, *Bb1 = nullptr;
  int mt, nt, b;
  if (MODE == 0) {
    mt = logical >> 2; nt = logical & 3;      // mt 0..127, nt 0..3 (nt inner: A-panel shared)
    b = mt >> 2;
    Ab0 = P0 + (size_t)mt * BM * DD;
    Bb0 = P1 + (size_t)nt * BN_T * DD;
  } else {
    b = logical >> 4; int r = logical & 15; mt = r >> 2; nt = r & 3;
    size_t bo = (size_t)b * BE;
    Ab0 = P0 + bo + (size_t)mt * BM * DD;     // adjnb
    Bb0 = P1 + bo + (size_t)nt * BN_T * DD;   // e1T
    Ab1 = P2 + bo + (size_t)mt * BM * DD;     // Xb
    Bb1 = P3 + (size_t)nt * BN_T * DD;        // WlT
  }

  // staging: 24 chunks of 1KB (16 rows x 64B). chunks 0-11 = A, 12-23 = B.
  // wave w stages chunks 6w..6w+5 (wave-uniform A/B split). 6 loads/thread.
  const int r_in = lane >> 2;                 // row within 16-row chunk
  const int s_in = lane & 3;                  // 16B slot

  auto stage = [&](int s) {
    const int buf = (s & 1) * BUFSZ;
    const unsigned short *Ab, *Bb;
    int kk;
    if (MODE == 1 && s >= 24) { kk = s - 24; Ab = Ab1; Bb = Bb1; }
    else                      { kk = s;      Ab = Ab0; Bb = Bb0; }
    #pragma unroll
    for (int i = 0; i < 6; ++i) {
      int chunk = wid * 6 + i;
      bool isA = chunk < 12;                  // wave-uniform
      int c = isA ? chunk : chunk - 12;
      int row = c * 16 + r_in;
      int slot = s_in ^ ((row >> 1) & 3);
      const unsigned short* src = (isA ? Ab : Bb) + (size_t)row * DD + kk * BK + slot * 8;
      __builtin_amdgcn_global_load_lds(
          (const __attribute__((address_space(1))) void*)src,
          (__attribute__((address_space(3))) void*)(smem + buf + (isA ? 0 : ABUF) + c * 1024),
          16, 0, 0);
    }
  };

  const int ks = lane >> 4;                   // k-slot 0..3 (8 elems each)
  auto frag = [&](int off, int row) -> bf16x8 {
    int slot = ks ^ ((row >> 1) & 3);
    return *reinterpret_cast<const bf16x8*>(smem + off + row * 64 + slot * 16);
  };

  f32x4 acc[6][6] = {};
  const int arow = wr * 96 + (lane & 15);
  const int brow = wc * 96 + (lane & 15);

  stage(0);

  for (int t = 0; t < NT; ++t) {
    asm volatile("s_waitcnt vmcnt(0)" ::: "memory");  // tile t landed (issued 1 tile ago)
    __builtin_amdgcn_s_barrier();

    if (t + 1 < NT) stage(t + 1);            // issue next tile ASAP (max slack)

    const int bufA = (t & 1) * BUFSZ;
    const int bufB = bufA + ABUF;
    bf16x8 a[6], bg[6];
    #pragma unroll
    for (int i = 0; i < 6; ++i) a[i] = frag(bufA, arow + i * 16);
    #pragma unroll
    for (int i = 0; i < 6; ++i) bg[i] = frag(bufB, brow + i * 16);

    __builtin_amdgcn_s_setprio(1);
    #pragma unroll
    for (int ni = 0; ni < 6; ++ni)           // ni outer: cluster ni needs b[ni] only
      #pragma unroll
      for (int mi = 0; mi < 6; ++mi)
        acc[mi][ni] = __builtin_amdgcn_mfma_f32_16x16x32_bf16(a[mi], bg[ni], acc[mi][ni], 0, 0, 0);
    __builtin_amdgcn_s_setprio(0);
  }

  // ---------------- epilogue ----------------
  if (MODE == 0) {
    unsigned short* ob = (unsigned short*)outp + (size_t)b * BE;
    const int mloc = (mt & 3) * BM + wr * 96 + (lane >> 4) * 4;
    #pragma unroll
    for (int mi = 0; mi < 6; ++mi)
      #pragma unroll
      for (int ni = 0; ni < 6; ++ni) {
        int m = mloc + mi * 16;
        int d = nt * BN_T + wc * 96 + ni * 16 + (lane & 15);
        f32x4 v = acc[mi][ni];
        ushort4 o;
        o.x = f2bf(v[0]); o.y = f2bf(v[1]); o.z = f2bf(v[2]); o.w = f2bf(v[3]);
        *reinterpret_cast<ushort4*>(ob + (size_t)d * DD + m) = o;  // e1T[d][m..m+3]
      }
  } else {
    float* ob = (float*)outp + (size_t)b * BE;
    const int mloc = mt * BM + wr * 96 + (lane >> 4) * 4;
    #pragma unroll
    for (int mi = 0; mi < 6; ++mi)
      #pragma unroll
      for (int ni = 0; ni < 6; ++ni) {
        int m = mloc + mi * 16;
        int n = nt * BN_T + wc * 96 + ni * 16 + (lane & 15);
        f32x4 v = acc[mi][ni];
        #pragma unroll
        for (int j = 0; j < 4; ++j) {
          float x = v[j];
          ob[(size_t)(m + j) * DD + n] = x > 0.f ? x : 0.01f * x;
        }
      }
  }
}

// ---------------- launch ----------------

extern "C" void kernel_launch(void* const* d_in, const int* in_sizes, int n_in,
                              void* d_out, int out_size, void* d_ws, size_t ws_size,
                              hipStream_t stream) {
  const float* X   = (const float*)d_in[0];
  const float* adj = (const float*)d_in[1];
  const float* Wl  = (const float*)d_in[2];
  const float* Wl1 = (const float*)d_in[3];
  float* out = (float*)d_out;

  char* ws = (char*)d_ws;
  const size_t SZ = (size_t)BN_ROWS * DD * 2;   // 37,748,736 bytes
  unsigned short* Xb    = (unsigned short*)(ws);
  unsigned short* adjnb = (unsigned short*)(ws + SZ);
  unsigned short* e1T   = (unsigned short*)(ws + 2 * SZ);
  unsigned short* WlT   = (unsigned short*)(ws + 3 * SZ);
  unsigned short* Wl1T  = (unsigned short*)(ws + 3 * SZ + (size_t)BE * 2);

  prep<<<PREP_CX + PREP_WT + PREP_AN, 256, 0, stream>>>(X, adj, Wl, Wl1,
                                                        Xb, adjnb, WlT, Wl1T);
  gemm4<0><<<512, 256, 0, stream>>>(Xb, Wl1T, nullptr, nullptr, e1T);
  gemm4<1><<<512, 256, 0, stream>>>(adjnb, e1T, Xb, WlT, out);
}